// Round 1
// baseline (232.047 us; speedup 1.0000x reference)
//
#include <hip/hip_runtime.h>

// Problem constants (match reference)
constexpr int BB = 256;
constexpr int SS = 8192;
constexpr int NPOS = BB * SS;          // 2,097,152 positions
constexpr int IGNORE = -100;
// GAMMA = 2.0 -> (1-pt)^2

__device__ __forceinline__ void focal_acc(float l0, float l1, float l2,
                                          int lab, float& fl, float& cnt) {
    if (lab == IGNORE) return;
    float m   = fmaxf(l0, fmaxf(l1, l2));
    float s   = __expf(l0 - m) + __expf(l1 - m) + __expf(l2 - m);
    float lse = m + __logf(s);
    float x   = (lab == 0) ? l0 : ((lab == 1) ? l1 : l2);
    float ce  = lse - x;
    float pt  = __expf(-ce);
    float om  = 1.0f - pt;
    fl  += om * om * ce;
    cnt += 1.0f;
}

__device__ __forceinline__ float bce_term(float z, float y) {
    // max(z,0) - z*y + log1p(exp(-|z|))
    return fmaxf(z, 0.0f) - z * y + __logf(1.0f + __expf(-fabsf(z)));
}

__global__ __launch_bounds__(256)
void main_kernel(const float* __restrict__ a_logits,
                 const float* __restrict__ o_logits,
                 const float* __restrict__ b_logits,
                 const int*   __restrict__ a_labels,
                 const int*   __restrict__ o_labels,
                 double*      __restrict__ ws) {
    int t = blockIdx.x * blockDim.x + threadIdx.x;   // [0, NPOS/4)
    float fl_a = 0.f, cnt_a = 0.f, fl_o = 0.f, cnt_o = 0.f, bce = 0.f;

    if (t < NPOS / 4) {
        int p0 = t * 4;                  // first of 4 consecutive positions

        // labels: int4 (16B aligned)
        int4 al4 = *(const int4*)(a_labels + p0);
        int4 ol4 = *(const int4*)(o_labels + p0);
        int al[5] = {al4.x, al4.y, al4.z, al4.w, -1};
        int ol[5] = {ol4.x, ol4.y, ol4.z, ol4.w, -1};
        int s3 = (p0 + 3) & (SS - 1);
        if (s3 != SS - 1) {              // next label lives in the next group
            al[4] = a_labels[p0 + 4];
            ol[4] = o_labels[p0 + 4];
        }

        // span logits: 12 floats = 3x float4 (48B-aligned since 48*t bytes)
        const float4* ap = (const float4*)(a_logits + p0 * 3);
        const float4* op = (const float4*)(o_logits + p0 * 3);
        float4 A0 = ap[0], A1 = ap[1], A2 = ap[2];
        float4 O0 = op[0], O1 = op[1], O2 = op[2];
        float aL[12] = {A0.x, A0.y, A0.z, A0.w, A1.x, A1.y, A1.z, A1.w,
                        A2.x, A2.y, A2.z, A2.w};
        float oL[12] = {O0.x, O0.y, O0.z, O0.w, O1.x, O1.y, O1.z, O1.w,
                        O2.x, O2.y, O2.z, O2.w};

        // boundary logits: 8 floats = 2x float4 (32B-aligned)
        const float4* bp = (const float4*)(b_logits + p0 * 2);
        float4 Z0 = bp[0], Z1 = bp[1];
        float z[8] = {Z0.x, Z0.y, Z0.z, Z0.w, Z1.x, Z1.y, Z1.z, Z1.w};

        #pragma unroll
        for (int j = 0; j < 4; ++j) {
            focal_acc(aL[3*j], aL[3*j+1], aL[3*j+2], al[j], fl_a, cnt_a);
            focal_acc(oL[3*j], oL[3*j+1], oL[3*j+2], ol[j], fl_o, cnt_o);
            float ys = ((al[j] == 1) || (ol[j] == 1)) ? 1.0f : 0.0f;
            float ye = (((al[j] == 2) && (al[j+1] != 2)) ||
                        ((ol[j] == 2) && (ol[j+1] != 2))) ? 1.0f : 0.0f;
            bce += bce_term(z[2*j],     ys);
            bce += bce_term(z[2*j + 1], ye);
        }
    }

    // block reduction: wave64 shuffle -> LDS -> thread0 atomics
    float vals[5] = {fl_a, cnt_a, fl_o, cnt_o, bce};
    #pragma unroll
    for (int k = 0; k < 5; ++k) {
        float v = vals[k];
        #pragma unroll
        for (int o = 32; o > 0; o >>= 1) v += __shfl_down(v, o, 64);
        vals[k] = v;
    }
    __shared__ float lds[4 * 5];
    int lane = threadIdx.x & 63, wid = threadIdx.x >> 6;
    if (lane == 0) {
        #pragma unroll
        for (int k = 0; k < 5; ++k) lds[wid * 5 + k] = vals[k];
    }
    __syncthreads();
    if (threadIdx.x == 0) {
        #pragma unroll
        for (int k = 0; k < 5; ++k) {
            float s = lds[k] + lds[5 + k] + lds[10 + k] + lds[15 + k];
            atomicAdd(&ws[k], (double)s);
        }
    }
}

__global__ __launch_bounds__(256)
void sent_final_kernel(const float* __restrict__ s_logits,
                       const int*   __restrict__ s_labels,
                       const double* __restrict__ ws,
                       float* __restrict__ out) {
    int b = threadIdx.x;                 // 256 threads, one per batch row
    float ce = 0.f, cnt = 0.f;
    if (b < BB) {
        int lab = s_labels[b];
        if (lab != IGNORE) {
            float l0 = s_logits[3*b], l1 = s_logits[3*b+1], l2 = s_logits[3*b+2];
            float m   = fmaxf(l0, fmaxf(l1, l2));
            float lse = m + __logf(__expf(l0-m) + __expf(l1-m) + __expf(l2-m));
            float x   = (lab == 0) ? l0 : ((lab == 1) ? l1 : l2);
            ce  = lse - x;
            cnt = 1.0f;
        }
    }
    float v = ce, c = cnt;
    #pragma unroll
    for (int o = 32; o > 0; o >>= 1) {
        v += __shfl_down(v, o, 64);
        c += __shfl_down(c, o, 64);
    }
    __shared__ float lds[8];
    int lane = threadIdx.x & 63, wid = threadIdx.x >> 6;
    if (lane == 0) { lds[wid] = v; lds[4 + wid] = c; }
    __syncthreads();
    if (threadIdx.x == 0) {
        float sv = lds[0] + lds[1] + lds[2] + lds[3];
        float sc = lds[4] + lds[5] + lds[6] + lds[7];
        double fl_a = ws[0], ca = ws[1], fl_o = ws[2], co = ws[3], bsum = ws[4];
        double aspect  = (ca > 0.0) ? fl_a / fmax(ca, 1.0) : 0.0;
        double opinion = (co > 0.0) ? fl_o / fmax(co, 1.0) : 0.0;
        double senti   = (double)sv / fmax((double)sc, 1.0);
        double bnd     = bsum / (double)((long long)NPOS * 2);
        out[0] = (float)(aspect + opinion + senti + 0.5 * bnd);
    }
}

extern "C" void kernel_launch(void* const* d_in, const int* in_sizes, int n_in,
                              void* d_out, int out_size, void* d_ws, size_t ws_size,
                              hipStream_t stream) {
    const float* a_logits = (const float*)d_in[0];   // (B,S,3)
    const float* o_logits = (const float*)d_in[1];   // (B,S,3)
    const float* s_logits = (const float*)d_in[2];   // (B,3)
    const float* b_logits = (const float*)d_in[3];   // (B,S,2)
    const int*   a_labels = (const int*)d_in[4];     // (B,S)
    const int*   o_labels = (const int*)d_in[5];     // (B,S)
    const int*   s_labels = (const int*)d_in[6];     // (B,)
    float* out = (float*)d_out;
    double* ws = (double*)d_ws;

    hipMemsetAsync(ws, 0, 5 * sizeof(double), stream);

    int nthreads = NPOS / 4;                          // 524288
    int blocks = nthreads / 256;                      // 2048
    main_kernel<<<blocks, 256, 0, stream>>>(a_logits, o_logits, b_logits,
                                            a_labels, o_labels, ws);
    sent_final_kernel<<<1, 256, 0, stream>>>(s_logits, s_labels, ws, out);
}

// Round 2
// 116.500 us; speedup vs baseline: 1.9918x; 1.9918x over previous
//
#include <hip/hip_runtime.h>

// Problem constants (match reference)
constexpr int BB = 256;
constexpr int SS = 8192;
constexpr int NPOS = BB * SS;          // 2,097,152 positions
constexpr int IGNORE = -100;
constexpr int BLOCKS = NPOS / 4 / 256; // 2048 blocks, 4 positions/thread
// GAMMA = 2.0 -> (1-pt)^2

__device__ __forceinline__ void focal_acc(float l0, float l1, float l2,
                                          int lab, float& fl, float& cnt) {
    if (lab == IGNORE) return;
    float m   = fmaxf(l0, fmaxf(l1, l2));
    float s   = __expf(l0 - m) + __expf(l1 - m) + __expf(l2 - m);
    float lse = m + __logf(s);
    float x   = (lab == 0) ? l0 : ((lab == 1) ? l1 : l2);
    float ce  = lse - x;
    float pt  = __expf(-ce);
    float om  = 1.0f - pt;
    fl  += om * om * ce;
    cnt += 1.0f;
}

__device__ __forceinline__ float bce_term(float z, float y) {
    // max(z,0) - z*y + log1p(exp(-|z|))
    return fmaxf(z, 0.0f) - z * y + __logf(1.0f + __expf(-fabsf(z)));
}

// ws layout: float partial[5][BLOCKS]  (5 * 2048 * 4B = 40 KB)
__global__ __launch_bounds__(256)
void main_kernel(const float* __restrict__ a_logits,
                 const float* __restrict__ o_logits,
                 const float* __restrict__ b_logits,
                 const int*   __restrict__ a_labels,
                 const int*   __restrict__ o_labels,
                 float*       __restrict__ partial) {
    int t = blockIdx.x * blockDim.x + threadIdx.x;   // [0, NPOS/4)
    float fl_a = 0.f, cnt_a = 0.f, fl_o = 0.f, cnt_o = 0.f, bce = 0.f;

    {
        int p0 = t * 4;                  // first of 4 consecutive positions

        // labels: int4 (16B aligned)
        int4 al4 = *(const int4*)(a_labels + p0);
        int4 ol4 = *(const int4*)(o_labels + p0);
        int al[5] = {al4.x, al4.y, al4.z, al4.w, -1};
        int ol[5] = {ol4.x, ol4.y, ol4.z, ol4.w, -1};
        int s3 = (p0 + 3) & (SS - 1);
        if (s3 != SS - 1) {              // next label lives in the next group
            al[4] = a_labels[p0 + 4];
            ol[4] = o_labels[p0 + 4];
        }

        // span logits: 12 floats = 3x float4 (48B-aligned since 48*t bytes)
        const float4* ap = (const float4*)(a_logits + p0 * 3);
        const float4* op = (const float4*)(o_logits + p0 * 3);
        float4 A0 = ap[0], A1 = ap[1], A2 = ap[2];
        float4 O0 = op[0], O1 = op[1], O2 = op[2];
        float aL[12] = {A0.x, A0.y, A0.z, A0.w, A1.x, A1.y, A1.z, A1.w,
                        A2.x, A2.y, A2.z, A2.w};
        float oL[12] = {O0.x, O0.y, O0.z, O0.w, O1.x, O1.y, O1.z, O1.w,
                        O2.x, O2.y, O2.z, O2.w};

        // boundary logits: 8 floats = 2x float4 (32B-aligned)
        const float4* bp = (const float4*)(b_logits + p0 * 2);
        float4 Z0 = bp[0], Z1 = bp[1];
        float z[8] = {Z0.x, Z0.y, Z0.z, Z0.w, Z1.x, Z1.y, Z1.z, Z1.w};

        #pragma unroll
        for (int j = 0; j < 4; ++j) {
            focal_acc(aL[3*j], aL[3*j+1], aL[3*j+2], al[j], fl_a, cnt_a);
            focal_acc(oL[3*j], oL[3*j+1], oL[3*j+2], ol[j], fl_o, cnt_o);
            float ys = ((al[j] == 1) || (ol[j] == 1)) ? 1.0f : 0.0f;
            float ye = (((al[j] == 2) && (al[j+1] != 2)) ||
                        ((ol[j] == 2) && (ol[j+1] != 2))) ? 1.0f : 0.0f;
            bce += bce_term(z[2*j],     ys);
            bce += bce_term(z[2*j + 1], ye);
        }
    }

    // block reduction: wave64 shuffle -> LDS -> thread0 writes block partial
    float vals[5] = {fl_a, cnt_a, fl_o, cnt_o, bce};
    #pragma unroll
    for (int k = 0; k < 5; ++k) {
        float v = vals[k];
        #pragma unroll
        for (int o = 32; o > 0; o >>= 1) v += __shfl_down(v, o, 64);
        vals[k] = v;
    }
    __shared__ float lds[4 * 5];
    int lane = threadIdx.x & 63, wid = threadIdx.x >> 6;
    if (lane == 0) {
        #pragma unroll
        for (int k = 0; k < 5; ++k) lds[wid * 5 + k] = vals[k];
    }
    __syncthreads();
    if (threadIdx.x == 0) {
        #pragma unroll
        for (int k = 0; k < 5; ++k) {
            float s = lds[k] + lds[5 + k] + lds[10 + k] + lds[15 + k];
            partial[k * BLOCKS + blockIdx.x] = s;   // plane layout, no atomics
        }
    }
}

__global__ __launch_bounds__(256)
void sent_final_kernel(const float* __restrict__ s_logits,
                       const int*   __restrict__ s_labels,
                       const float* __restrict__ partial,
                       float* __restrict__ out) {
    int tid = threadIdx.x;               // 256 threads

    // --- reduce the 5 partial planes (2048 each, coalesced) ---
    float acc[5];
    #pragma unroll
    for (int k = 0; k < 5; ++k) {
        float s = 0.f;
        #pragma unroll
        for (int i = 0; i < BLOCKS / 256; ++i)     // 8 iters
            s += partial[k * BLOCKS + tid + i * 256];
        acc[k] = s;
    }

    // --- sentiment CE (one element per thread, B=256) ---
    float ce = 0.f, cnt = 0.f;
    {
        int lab = s_labels[tid];
        if (lab != IGNORE) {
            float l0 = s_logits[3*tid], l1 = s_logits[3*tid+1], l2 = s_logits[3*tid+2];
            float m   = fmaxf(l0, fmaxf(l1, l2));
            float lse = m + __logf(__expf(l0-m) + __expf(l1-m) + __expf(l2-m));
            float x   = (lab == 0) ? l0 : ((lab == 1) ? l1 : l2);
            ce  = lse - x;
            cnt = 1.0f;
        }
    }

    float vals[7] = {acc[0], acc[1], acc[2], acc[3], acc[4], ce, cnt};
    #pragma unroll
    for (int k = 0; k < 7; ++k) {
        float v = vals[k];
        #pragma unroll
        for (int o = 32; o > 0; o >>= 1) v += __shfl_down(v, o, 64);
        vals[k] = v;
    }
    __shared__ float lds[4 * 7];
    int lane = threadIdx.x & 63, wid = threadIdx.x >> 6;
    if (lane == 0) {
        #pragma unroll
        for (int k = 0; k < 7; ++k) lds[wid * 7 + k] = vals[k];
    }
    __syncthreads();
    if (threadIdx.x == 0) {
        float tot[7];
        #pragma unroll
        for (int k = 0; k < 7; ++k)
            tot[k] = lds[k] + lds[7 + k] + lds[14 + k] + lds[21 + k];
        double fl_a = tot[0], ca = tot[1], fl_o = tot[2], co = tot[3];
        double bsum = tot[4], sv = tot[5], sc = tot[6];
        double aspect  = (ca > 0.0) ? fl_a / fmax(ca, 1.0) : 0.0;
        double opinion = (co > 0.0) ? fl_o / fmax(co, 1.0) : 0.0;
        double senti   = sv / fmax(sc, 1.0);
        double bnd     = bsum / (double)((long long)NPOS * 2);
        out[0] = (float)(aspect + opinion + senti + 0.5 * bnd);
    }
}

extern "C" void kernel_launch(void* const* d_in, const int* in_sizes, int n_in,
                              void* d_out, int out_size, void* d_ws, size_t ws_size,
                              hipStream_t stream) {
    const float* a_logits = (const float*)d_in[0];   // (B,S,3)
    const float* o_logits = (const float*)d_in[1];   // (B,S,3)
    const float* s_logits = (const float*)d_in[2];   // (B,3)
    const float* b_logits = (const float*)d_in[3];   // (B,S,2)
    const int*   a_labels = (const int*)d_in[4];     // (B,S)
    const int*   o_labels = (const int*)d_in[5];     // (B,S)
    const int*   s_labels = (const int*)d_in[6];     // (B,)
    float* out = (float*)d_out;
    float* partial = (float*)d_ws;                   // 5 * 2048 floats = 40 KB

    main_kernel<<<BLOCKS, 256, 0, stream>>>(a_logits, o_logits, b_logits,
                                            a_labels, o_labels, partial);
    sent_final_kernel<<<1, 256, 0, stream>>>(s_logits, s_labels, partial, out);
}

// Round 3
// 116.024 us; speedup vs baseline: 2.0000x; 1.0041x over previous
//
#include <hip/hip_runtime.h>

// Problem constants (match reference)
constexpr int BB = 256;
constexpr int SS = 8192;
constexpr int NPOS = BB * SS;          // 2,097,152 positions
constexpr int IGNORE = -100;
constexpr int BLOCKS = NPOS / 4 / 256; // 2048 blocks, 4 positions/thread
// GAMMA = 2.0 -> (1-pt)^2

__device__ __forceinline__ void focal_acc(float l0, float l1, float l2,
                                          int lab, float& fl, float& cnt) {
    if (lab == IGNORE) return;
    float m   = fmaxf(l0, fmaxf(l1, l2));
    float s   = __expf(l0 - m) + __expf(l1 - m) + __expf(l2 - m);
    float lse = m + __logf(s);
    float x   = (lab == 0) ? l0 : ((lab == 1) ? l1 : l2);
    float ce  = lse - x;
    float pt  = __expf(-ce);
    float om  = 1.0f - pt;
    fl  += om * om * ce;
    cnt += 1.0f;
}

__device__ __forceinline__ float bce_term(float z, float y) {
    // max(z,0) - z*y + log1p(exp(-|z|))
    return fmaxf(z, 0.0f) - z * y + __logf(1.0f + __expf(-fabsf(z)));
}

// ws layout: float partial[5][BLOCKS]  (5 * 2048 * 4B = 40 KB)
__global__ __launch_bounds__(256)
void main_kernel(const float* __restrict__ a_logits,
                 const float* __restrict__ o_logits,
                 const float* __restrict__ b_logits,
                 const int*   __restrict__ a_labels,
                 const int*   __restrict__ o_labels,
                 float*       __restrict__ partial) {
    int t = blockIdx.x * blockDim.x + threadIdx.x;   // [0, NPOS/4)
    float fl_a = 0.f, cnt_a = 0.f, fl_o = 0.f, cnt_o = 0.f, bce = 0.f;

    {
        int p0 = t * 4;                  // first of 4 consecutive positions
        int lane = threadIdx.x & 63;

        // labels: int4 (16B aligned)
        int4 al4 = *(const int4*)(a_labels + p0);
        int4 ol4 = *(const int4*)(o_labels + p0);

        // next-label for position p0+3: lives in lane+1's al4.x (rows are
        // wave-aligned: row end only ever falls on lane 63's last position)
        int al_next = __shfl_down(al4.x, 1, 64);
        int ol_next = __shfl_down(ol4.x, 1, 64);
        if (lane == 63) {
            if (((p0 + 3) & (SS - 1)) != SS - 1) {
                al_next = a_labels[p0 + 4];
                ol_next = o_labels[p0 + 4];
            } else {
                al_next = -1;            // JAX concat(..., -1) sentinel
                ol_next = -1;
            }
        }
        int al[5] = {al4.x, al4.y, al4.z, al4.w, al_next};
        int ol[5] = {ol4.x, ol4.y, ol4.z, ol4.w, ol_next};

        // span logits: 12 floats = 3x float4 (48B-aligned since 48*t bytes)
        const float4* ap = (const float4*)(a_logits + p0 * 3);
        const float4* op = (const float4*)(o_logits + p0 * 3);
        float4 A0 = ap[0], A1 = ap[1], A2 = ap[2];
        float4 O0 = op[0], O1 = op[1], O2 = op[2];
        float aL[12] = {A0.x, A0.y, A0.z, A0.w, A1.x, A1.y, A1.z, A1.w,
                        A2.x, A2.y, A2.z, A2.w};
        float oL[12] = {O0.x, O0.y, O0.z, O0.w, O1.x, O1.y, O1.z, O1.w,
                        O2.x, O2.y, O2.z, O2.w};

        // boundary logits: 8 floats = 2x float4 (32B-aligned)
        const float4* bp = (const float4*)(b_logits + p0 * 2);
        float4 Z0 = bp[0], Z1 = bp[1];
        float z[8] = {Z0.x, Z0.y, Z0.z, Z0.w, Z1.x, Z1.y, Z1.z, Z1.w};

        #pragma unroll
        for (int j = 0; j < 4; ++j) {
            focal_acc(aL[3*j], aL[3*j+1], aL[3*j+2], al[j], fl_a, cnt_a);
            focal_acc(oL[3*j], oL[3*j+1], oL[3*j+2], ol[j], fl_o, cnt_o);
            float ys = ((al[j] == 1) || (ol[j] == 1)) ? 1.0f : 0.0f;
            float ye = (((al[j] == 2) && (al[j+1] != 2)) ||
                        ((ol[j] == 2) && (ol[j+1] != 2))) ? 1.0f : 0.0f;
            bce += bce_term(z[2*j],     ys);
            bce += bce_term(z[2*j + 1], ye);
        }
    }

    // block reduction: wave64 shuffle -> LDS -> thread0 writes block partial
    float vals[5] = {fl_a, cnt_a, fl_o, cnt_o, bce};
    #pragma unroll
    for (int k = 0; k < 5; ++k) {
        float v = vals[k];
        #pragma unroll
        for (int o = 32; o > 0; o >>= 1) v += __shfl_down(v, o, 64);
        vals[k] = v;
    }
    __shared__ float lds[4 * 5];
    int lane = threadIdx.x & 63, wid = threadIdx.x >> 6;
    if (lane == 0) {
        #pragma unroll
        for (int k = 0; k < 5; ++k) lds[wid * 5 + k] = vals[k];
    }
    __syncthreads();
    if (threadIdx.x == 0) {
        #pragma unroll
        for (int k = 0; k < 5; ++k) {
            float s = lds[k] + lds[5 + k] + lds[10 + k] + lds[15 + k];
            partial[k * BLOCKS + blockIdx.x] = s;   // plane layout, no atomics
        }
    }
}

__global__ __launch_bounds__(256)
void sent_final_kernel(const float* __restrict__ s_logits,
                       const int*   __restrict__ s_labels,
                       const float* __restrict__ partial,
                       float* __restrict__ out) {
    int tid = threadIdx.x;               // 256 threads

    // --- reduce the 5 partial planes (2048 each, coalesced) ---
    float acc[5];
    #pragma unroll
    for (int k = 0; k < 5; ++k) {
        float s = 0.f;
        #pragma unroll
        for (int i = 0; i < BLOCKS / 256; ++i)     // 8 iters
            s += partial[k * BLOCKS + tid + i * 256];
        acc[k] = s;
    }

    // --- sentiment CE (one element per thread, B=256) ---
    float ce = 0.f, cnt = 0.f;
    {
        int lab = s_labels[tid];
        if (lab != IGNORE) {
            float l0 = s_logits[3*tid], l1 = s_logits[3*tid+1], l2 = s_logits[3*tid+2];
            float m   = fmaxf(l0, fmaxf(l1, l2));
            float lse = m + __logf(__expf(l0-m) + __expf(l1-m) + __expf(l2-m));
            float x   = (lab == 0) ? l0 : ((lab == 1) ? l1 : l2);
            ce  = lse - x;
            cnt = 1.0f;
        }
    }

    float vals[7] = {acc[0], acc[1], acc[2], acc[3], acc[4], ce, cnt};
    #pragma unroll
    for (int k = 0; k < 7; ++k) {
        float v = vals[k];
        #pragma unroll
        for (int o = 32; o > 0; o >>= 1) v += __shfl_down(v, o, 64);
        vals[k] = v;
    }
    __shared__ float lds[4 * 7];
    int lane = threadIdx.x & 63, wid = threadIdx.x >> 6;
    if (lane == 0) {
        #pragma unroll
        for (int k = 0; k < 7; ++k) lds[wid * 7 + k] = vals[k];
    }
    __syncthreads();
    if (threadIdx.x == 0) {
        float tot[7];
        #pragma unroll
        for (int k = 0; k < 7; ++k)
            tot[k] = lds[k] + lds[7 + k] + lds[14 + k] + lds[21 + k];
        double fl_a = tot[0], ca = tot[1], fl_o = tot[2], co = tot[3];
        double bsum = tot[4], sv = tot[5], sc = tot[6];
        double aspect  = (ca > 0.0) ? fl_a / fmax(ca, 1.0) : 0.0;
        double opinion = (co > 0.0) ? fl_o / fmax(co, 1.0) : 0.0;
        double senti   = sv / fmax(sc, 1.0);
        double bnd     = bsum / (double)((long long)NPOS * 2);
        out[0] = (float)(aspect + opinion + senti + 0.5 * bnd);
    }
}

extern "C" void kernel_launch(void* const* d_in, const int* in_sizes, int n_in,
                              void* d_out, int out_size, void* d_ws, size_t ws_size,
                              hipStream_t stream) {
    const float* a_logits = (const float*)d_in[0];   // (B,S,3)
    const float* o_logits = (const float*)d_in[1];   // (B,S,3)
    const float* s_logits = (const float*)d_in[2];   // (B,3)
    const float* b_logits = (const float*)d_in[3];   // (B,S,2)
    const int*   a_labels = (const int*)d_in[4];     // (B,S)
    const int*   o_labels = (const int*)d_in[5];     // (B,S)
    const int*   s_labels = (const int*)d_in[6];     // (B,)
    float* out = (float*)d_out;
    float* partial = (float*)d_ws;                   // 5 * 2048 floats = 40 KB

    main_kernel<<<BLOCKS, 256, 0, stream>>>(a_logits, o_logits, b_logits,
                                            a_labels, o_labels, partial);
    sent_final_kernel<<<1, 256, 0, stream>>>(s_logits, s_labels, partial, out);
}